// Round 9
// baseline (579.692 us; speedup 1.0000x reference)
//
#include <hip/hip_runtime.h>

// Problem constants
#define N_NODES_C 100000
#define N_EDGES_C 200000
#define N_INC_C   1600000
#define F_IN_C    128
#define H1_C      64
#define H2_C      128
#define NV 8   // histogram copies (~XCDs)

// ---------------- workspace layout (units of 4 bytes) ----------------
static constexpr size_t U_HIST_E = 0;          // 200000 (int)  totals for scan
static constexpr size_t U_HIST_N = 200000;     // 100000 (int)
static constexpr size_t U_RPE    = 300000;     // 200001 (int)
static constexpr size_t U_RPN    = 500032;     // 100001 (int)
static constexpr size_t U_BSUM   = 600064;     // 256    (int)
static constexpr size_t U_COEF   = 600320;     // 200000 (float)
static constexpr size_t U_DINV   = 800320;     // 100000 (float)
static constexpr size_t U_H8E    = 900320;     // 1600000 (int)  8 x 200000, memset
static constexpr size_t U_H8N    = 2500320;    // 800000  (int)  8 x 100000, memset
static constexpr size_t U_RANK_E = 3300320;    // 1600000 (int)
static constexpr size_t U_RANK_N = 4900320;    // 1600000 (int)
static constexpr size_t U_CSR_EN = 6500320;    // 1600000 (int)  edge -> node ids
static constexpr size_t U_CSR_NE = 8100320;    // 1600000 (int)  node -> edge ids
static constexpr size_t U_R2     = 9700320;    // 6400000 (float) h1 / g1 / t2
static constexpr size_t U_R1     = 16100320;   // 12800000 (float) e1 / s2
// total = 28900320 * 4 B = 115.6 MB

// ---------------- CSR build ----------------

// XCD-privatized histogram + per-incidence local rank.
// v = blockIdx.x & 7 round-robins onto XCDs; atomics stay in one XCD's L2.
// Place kernels MUST use the same grid so v is recomputed identically.
__global__ void k_hist_rank8(const int* __restrict__ nidx, const int* __restrict__ eidx,
                             int* __restrict__ hist8_n, int* __restrict__ hist8_e,
                             int* __restrict__ rank_n, int* __restrict__ rank_e) {
    int v = blockIdx.x & (NV - 1);
    int* he = hist8_e + (size_t)v * N_EDGES_C;
    int* hn = hist8_n + (size_t)v * N_NODES_C;
    int i = blockIdx.x * blockDim.x + threadIdx.x;
    int stride = gridDim.x * blockDim.x;
    for (; i < N_INC_C; i += stride) {
        rank_e[i] = atomicAdd(&he[eidx[i]], 1);
        rank_n[i] = atomicAdd(&hn[nidx[i]], 1);
    }
}

// hist8[v][k] -> exclusive prefix over v (in place); total -> hist[k]
__global__ void k_merge8(int* __restrict__ hist8, int* __restrict__ hist, int n) {
    int k = blockIdx.x * blockDim.x + threadIdx.x;
    if (k >= n) return;
    int s = 0;
#pragma unroll
    for (int v = 0; v < NV; ++v) {
        int h = hist8[(size_t)v * n + k];
        hist8[(size_t)v * n + k] = s;
        s += h;
    }
    hist[k] = s;
}

// hist8[v][k] += rowptr[k]  (fold CSR base so place does one random read)
__global__ void k_fold8(int* __restrict__ hist8, const int* __restrict__ rowptr, int n) {
    int k = blockIdx.x * blockDim.x + threadIdx.x;
    if (k >= n) return;
    int r = rowptr[k];
#pragma unroll
    for (int v = 0; v < NV; ++v) hist8[(size_t)v * n + k] += r;
}

#define SCAN_ITEMS 8
#define SCAN_CHUNK 2048  // 256 threads * 8

__global__ __launch_bounds__(256) void k_scan_block_sums(const int* __restrict__ in,
                                                         int* __restrict__ bsum, int n) {
    __shared__ int lds[4];
    int base = blockIdx.x * SCAN_CHUNK + threadIdx.x * SCAN_ITEMS;
    int s = 0;
#pragma unroll
    for (int j = 0; j < SCAN_ITEMS; ++j) {
        int idx = base + j;
        s += (idx < n) ? in[idx] : 0;
    }
    for (int d = 1; d < 64; d <<= 1) s += __shfl_xor(s, d);
    if ((threadIdx.x & 63) == 0) lds[threadIdx.x >> 6] = s;
    __syncthreads();
    if (threadIdx.x == 0) bsum[blockIdx.x] = lds[0] + lds[1] + lds[2] + lds[3];
}

// single block of 64 threads, exclusive-scans bsum[0..nb), nb <= 128
__global__ void k_scan_bsum(int* bsum, int nb) {
    int t = threadIdx.x;
    int v0 = (2 * t < nb) ? bsum[2 * t] : 0;
    int v1 = (2 * t + 1 < nb) ? bsum[2 * t + 1] : 0;
    int s = v0 + v1;
    int incl = s;
    for (int d = 1; d < 64; d <<= 1) {
        int u = __shfl_up(incl, d);
        if (t >= d) incl += u;
    }
    int excl = incl - s;
    if (2 * t < nb) bsum[2 * t] = excl;
    if (2 * t + 1 < nb) bsum[2 * t + 1] = excl + v0;
}

__global__ __launch_bounds__(256) void k_scan_write(const int* __restrict__ in,
                                                    const int* __restrict__ bsum,
                                                    int* __restrict__ rowptr, int n, int total) {
    __shared__ int wsum[4];
    int tid = threadIdx.x;
    int base = blockIdx.x * SCAN_CHUNK + tid * SCAN_ITEMS;
    int v[SCAN_ITEMS];
    int s = 0;
#pragma unroll
    for (int j = 0; j < SCAN_ITEMS; ++j) {
        int idx = base + j;
        v[j] = (idx < n) ? in[idx] : 0;
        s += v[j];
    }
    int incl = s;
    int lane = tid & 63;
    for (int d = 1; d < 64; d <<= 1) {
        int u = __shfl_up(incl, d);
        if (lane >= d) incl += u;
    }
    if (lane == 63) wsum[tid >> 6] = incl;
    __syncthreads();
    int woff = 0;
    int w = tid >> 6;
    for (int i = 0; i < w; ++i) woff += wsum[i];
    int excl = woff + (incl - s) + bsum[blockIdx.x];
#pragma unroll
    for (int j = 0; j < SCAN_ITEMS; ++j) {
        int idx = base + j;
        if (idx < n) rowptr[idx] = excl;
        excl += v[j];
    }
    if (blockIdx.x == 0 && tid == 0) rowptr[n] = total;
}

// placement: one random-write stream per kernel, no atomics
__global__ void k_place_e(const int* __restrict__ nidx, const int* __restrict__ eidx,
                          const int* __restrict__ rank_e, const int* __restrict__ off8_e,
                          int* __restrict__ csr_e_n) {
    int v = blockIdx.x & (NV - 1);
    const int* off = off8_e + (size_t)v * N_EDGES_C;
    int i = blockIdx.x * blockDim.x + threadIdx.x;
    int stride = gridDim.x * blockDim.x;
    for (; i < N_INC_C; i += stride)
        csr_e_n[off[eidx[i]] + rank_e[i]] = nidx[i];
}

__global__ void k_place_n(const int* __restrict__ nidx, const int* __restrict__ eidx,
                          const int* __restrict__ rank_n, const int* __restrict__ off8_n,
                          int* __restrict__ csr_n_e) {
    int v = blockIdx.x & (NV - 1);
    const int* off = off8_n + (size_t)v * N_NODES_C;
    int i = blockIdx.x * blockDim.x + threadIdx.x;
    int stride = gridDim.x * blockDim.x;
    for (; i < N_INC_C; i += stride)
        csr_n_e[off[nidx[i]] + rank_n[i]] = eidx[i];
}

__global__ void k_coef(const float* __restrict__ w, const int* __restrict__ rpe,
                       float* __restrict__ coef) {
    int i = blockIdx.x * blockDim.x + threadIdx.x;
    if (i >= N_EDGES_C) return;
    int bd = rpe[i + 1] - rpe[i];
    coef[i] = (bd > 0) ? w[i] / (float)bd : 0.0f;
}

__global__ void k_dinv(const int* __restrict__ rpn, const int* __restrict__ csr_n_e,
                       const float* __restrict__ w, float* __restrict__ Dinv) {
    int i = blockIdx.x * blockDim.x + threadIdx.x;
    if (i >= N_NODES_C) return;
    int s0 = rpn[i], s1 = rpn[i + 1];
    float s = 0.0f;
    for (int k = s0; k < s1; ++k) s += w[csr_n_e[k]];
    Dinv[i] = (s > 0.0f) ? 1.0f / s : 0.0f;
}

// ---------------- register-tiled dense GEMM ----------------
// Y[nrows x N] = X[nrows x K] @ W[K x N] (+bias, relu if EPI)
// 256 threads = 16 col-groups (tx) x 16 row-groups (ty); thread tile TM x TN.
template <int K, int N, int BM, int TM, int TN, int EPI>
__global__ __launch_bounds__(256) void k_gemm_rt(const float* __restrict__ X,
                                                 const float* __restrict__ W,
                                                 const float* __restrict__ bias,
                                                 float* __restrict__ Y, int nrows) {
    static_assert(16 * TN == N && 16 * TM == BM, "tile mismatch");
    __shared__ float Ws[K * N];
    __shared__ float Xs[BM][K + 4];   // +4: rows stay 16B-aligned, banks staggered

    int tid = threadIdx.x;
    int row0 = blockIdx.x * BM;

    // stage W (whole K x N) via float4
    for (int t = tid * 4; t < K * N; t += 1024)
        *reinterpret_cast<float4*>(&Ws[t]) = *reinterpret_cast<const float4*>(&W[t]);
    // stage X tile via float4
    for (int t = tid * 4; t < BM * K; t += 1024) {
        int r = t / K, k = t % K;
        int gr = row0 + r;
        float4 v;
        if (gr < nrows) v = *reinterpret_cast<const float4*>(&X[(size_t)gr * K + k]);
        else { v.x = v.y = v.z = v.w = 0.0f; }
        *reinterpret_cast<float4*>(&Xs[r][k]) = v;
    }
    __syncthreads();

    int tx = tid & 15;
    int ty = tid >> 4;
    float acc[TM][TN] = {};
#pragma unroll 8
    for (int k = 0; k < K; ++k) {
        float a[TM], b[TN];
#pragma unroll
        for (int m = 0; m < TM; ++m) a[m] = Xs[ty * TM + m][k];
#pragma unroll
        for (int n = 0; n < TN; ++n) b[n] = Ws[k * N + tx * TN + n];
#pragma unroll
        for (int m = 0; m < TM; ++m)
#pragma unroll
            for (int n = 0; n < TN; ++n) acc[m][n] += a[m] * b[n];
    }

#pragma unroll
    for (int m = 0; m < TM; ++m) {
        int gr = row0 + ty * TM + m;
        if (gr >= nrows) continue;
#pragma unroll
        for (int ng = 0; ng < TN / 4; ++ng) {
            float4 o;
            o.x = acc[m][ng * 4 + 0]; o.y = acc[m][ng * 4 + 1];
            o.z = acc[m][ng * 4 + 2]; o.w = acc[m][ng * 4 + 3];
            if (EPI) {
                const float4 b4 = *reinterpret_cast<const float4*>(&bias[tx * TN + ng * 4]);
                o.x += b4.x; o.y += b4.y; o.z += b4.z; o.w += b4.w;
                o.x = o.x > 0.0f ? o.x : 0.0f;
                o.y = o.y > 0.0f ? o.y : 0.0f;
                o.z = o.z > 0.0f ? o.z : 0.0f;
                o.w = o.w > 0.0f ? o.w : 0.0f;
            }
            *reinterpret_cast<float4*>(&Y[(size_t)gr * N + tx * TN + ng * 4]) = o;
        }
    }
}

// ---------------- CSR gathers: 4 neighbor-groups x 16 lanes x float4 ----------------
// EN=0: dst[r] = sum_{c in row} src[c]            (node -> edge)
// EN=1: dst[r] = Dinv[r] * sum coef[c]*src[c]     (edge -> node), FIN: +bias, relu
template <int EN, int FIN>
__global__ __launch_bounds__(256) void k_gather_v4(const int* __restrict__ rowptr,
                                                   const int* __restrict__ cols,
                                                   const float* __restrict__ coef,
                                                   const float* __restrict__ src,
                                                   const float* __restrict__ Dinv,
                                                   const float* __restrict__ bias,
                                                   float* __restrict__ dst, int nrows) {
    int wid = (blockIdx.x * 256 + threadIdx.x) >> 6;
    int lane = threadIdx.x & 63;
    int g = lane >> 4;        // neighbor group 0..3
    int gl = lane & 15;       // lane within group -> channels [gl*4, gl*4+4)
    int nw = (gridDim.x * 256) >> 6;
    for (int r = wid; r < nrows; r += nw) {
        int s0 = rowptr[r], s1 = rowptr[r + 1];
        float ax = 0.0f, ay = 0.0f, az = 0.0f, aw = 0.0f;
        for (int j = s0 + g; j < s1; j += 4) {
            int c = cols[j];  // uniform within group
            float s = EN ? coef[c] : 1.0f;
            const float4 v = *reinterpret_cast<const float4*>(&src[(size_t)c * 64 + gl * 4]);
            ax += s * v.x; ay += s * v.y; az += s * v.z; aw += s * v.w;
        }
        // reduce the 4 neighbor groups
        ax += __shfl_xor(ax, 16); ay += __shfl_xor(ay, 16);
        az += __shfl_xor(az, 16); aw += __shfl_xor(aw, 16);
        ax += __shfl_xor(ax, 32); ay += __shfl_xor(ay, 32);
        az += __shfl_xor(az, 32); aw += __shfl_xor(aw, 32);
        if (g == 0) {
            float4 o;
            o.x = ax; o.y = ay; o.z = az; o.w = aw;
            if (EN) {
                float dv = Dinv[r];
                o.x *= dv; o.y *= dv; o.z *= dv; o.w *= dv;
            }
            if (FIN) {
                const float4 b4 = *reinterpret_cast<const float4*>(&bias[gl * 4]);
                o.x += b4.x; o.y += b4.y; o.z += b4.z; o.w += b4.w;
                o.x = o.x > 0.0f ? o.x : 0.0f;
                o.y = o.y > 0.0f ? o.y : 0.0f;
                o.z = o.z > 0.0f ? o.z : 0.0f;
                o.w = o.w > 0.0f ? o.w : 0.0f;
            }
            *reinterpret_cast<float4*>(&dst[(size_t)r * 64 + gl * 4]) = o;
        }
    }
}

// ---------------- host ----------------

extern "C" void kernel_launch(void* const* d_in, const int* in_sizes, int n_in,
                              void* d_out, int out_size, void* d_ws, size_t ws_size,
                              hipStream_t stream) {
    const float* x   = (const float*)d_in[0];
    const int*   eix = (const int*)d_in[1];
    const float* w   = (const float*)d_in[2];
    const float* W1  = (const float*)d_in[4];
    const float* b1  = (const float*)d_in[5];
    const float* W2  = (const float*)d_in[6];
    const float* b2  = (const float*)d_in[7];
    float* out = (float*)d_out;

    const int* nidx = eix;
    const int* eidx = eix + N_INC_C;

    int*   wsI = (int*)d_ws;
    float* wsF = (float*)d_ws;
    int* hist_e  = wsI + U_HIST_E;
    int* hist_n  = wsI + U_HIST_N;
    int* rpe     = wsI + U_RPE;
    int* rpn     = wsI + U_RPN;
    int* bsum    = wsI + U_BSUM;
    float* coef  = wsF + U_COEF;
    float* Dinv  = wsF + U_DINV;
    int* hist8_e = wsI + U_H8E;
    int* hist8_n = wsI + U_H8N;
    int* rank_e  = wsI + U_RANK_E;
    int* rank_n  = wsI + U_RANK_N;
    int* csr_e_n = wsI + U_CSR_EN;
    int* csr_n_e = wsI + U_CSR_NE;
    float* h1 = wsF + U_R2;   // [N_NODES x 64]
    float* g1 = wsF + U_R2;   // reuses h1 (h1 dead when g1 written)
    float* t2 = wsF + U_R2;   // reuses g1 (g1 dead when t2 written)
    float* e1 = wsF + U_R1;   // [N_EDGES x 64]
    float* s2 = wsF + U_R1;   // reuses e1

    // ---- CSR build ----
    hipMemsetAsync(hist8_e, 0, (size_t)(NV * N_EDGES_C + NV * N_NODES_C) * 4, stream);
    k_hist_rank8<<<2048, 256, 0, stream>>>(nidx, eidx, hist8_n, hist8_e, rank_n, rank_e);

    k_merge8<<<(N_EDGES_C + 255) / 256, 256, 0, stream>>>(hist8_e, hist_e, N_EDGES_C);
    k_merge8<<<(N_NODES_C + 255) / 256, 256, 0, stream>>>(hist8_n, hist_n, N_NODES_C);

    int nb_e = (N_EDGES_C + SCAN_CHUNK - 1) / SCAN_CHUNK;   // 98
    int nb_n = (N_NODES_C + SCAN_CHUNK - 1) / SCAN_CHUNK;   // 49
    k_scan_block_sums<<<nb_e, 256, 0, stream>>>(hist_e, bsum, N_EDGES_C);
    k_scan_bsum<<<1, 64, 0, stream>>>(bsum, nb_e);
    k_scan_write<<<nb_e, 256, 0, stream>>>(hist_e, bsum, rpe, N_EDGES_C, N_INC_C);
    k_scan_block_sums<<<nb_n, 256, 0, stream>>>(hist_n, bsum, N_NODES_C);
    k_scan_bsum<<<1, 64, 0, stream>>>(bsum, nb_n);
    k_scan_write<<<nb_n, 256, 0, stream>>>(hist_n, bsum, rpn, N_NODES_C, N_INC_C);

    k_fold8<<<(N_EDGES_C + 255) / 256, 256, 0, stream>>>(hist8_e, rpe, N_EDGES_C);
    k_fold8<<<(N_NODES_C + 255) / 256, 256, 0, stream>>>(hist8_n, rpn, N_NODES_C);

    k_place_e<<<2048, 256, 0, stream>>>(nidx, eidx, rank_e, hist8_e, csr_e_n);
    k_place_n<<<2048, 256, 0, stream>>>(nidx, eidx, rank_n, hist8_n, csr_n_e);
    k_coef<<<(N_EDGES_C + 255) / 256, 256, 0, stream>>>(w, rpe, coef);
    k_dinv<<<(N_NODES_C + 255) / 256, 256, 0, stream>>>(rpn, csr_n_e, w, Dinv);

    // ---- layer 1 ----
    k_gemm_rt<F_IN_C, H1_C, 32, 2, 4, 0><<<(N_NODES_C + 31) / 32, 256, 0, stream>>>(
        x, W1, nullptr, h1, N_NODES_C);
    k_gather_v4<0, 0><<<(N_EDGES_C + 3) / 4, 256, 0, stream>>>(rpe, csr_e_n, nullptr, h1,
                                                               nullptr, nullptr, e1, N_EDGES_C);
    k_gather_v4<1, 1><<<(N_NODES_C + 3) / 4, 256, 0, stream>>>(rpn, csr_n_e, coef, e1,
                                                               Dinv, b1, g1, N_NODES_C);

    // ---- layer 2 (aggregate in 64-dim, project 64->128 last) ----
    k_gather_v4<0, 0><<<(N_EDGES_C + 3) / 4, 256, 0, stream>>>(rpe, csr_e_n, nullptr, g1,
                                                               nullptr, nullptr, s2, N_EDGES_C);
    k_gather_v4<1, 0><<<(N_NODES_C + 3) / 4, 256, 0, stream>>>(rpn, csr_n_e, coef, s2,
                                                               Dinv, nullptr, t2, N_NODES_C);
    k_gemm_rt<H1_C, H2_C, 64, 4, 8, 1><<<(N_NODES_C + 63) / 64, 256, 0, stream>>>(
        t2, W2, b2, out, N_NODES_C);
}

// Round 11
// 497.102 us; speedup vs baseline: 1.1661x; 1.1661x over previous
//
#include <hip/hip_runtime.h>

// Problem constants
#define N_NODES_C 100000
#define N_EDGES_C 200000
#define N_INC_C   1600000
#define F_IN_C    128
#define H1_C      64
#define H2_C      128

typedef unsigned int uint;
typedef unsigned short ushort;

// ---------------- workspace layout (units of 4 bytes) ----------------
static constexpr size_t U_HIST_E = 0;          // 200000 (int)   memset [0,300000)
static constexpr size_t U_HIST_N = 200000;     // 100000 (int)
static constexpr size_t U_RPE    = 300000;     // 200001 (int)
static constexpr size_t U_RPN    = 500032;     // 100001 (int)
static constexpr size_t U_BSUM   = 600064;     // 256    (int)
static constexpr size_t U_COEF   = 600320;     // 200000 (float)
static constexpr size_t U_DINV   = 800320;     // 100000 (float)
static constexpr size_t U_RANK_E = 900320;     // 1600000 (int)
static constexpr size_t U_RANK_N = 2500320;    // 1600000 (int)
static constexpr size_t U_CSR_EN = 4100320;    // 1600000 (int)  edge -> node ids
static constexpr size_t U_CSR_NE = 5700320;    // 1600000 (int)  node -> edge ids
static constexpr size_t U_R2     = 7300320;    // 3200000 u32 = node bf16 buf (h1/g1/t2)
static constexpr size_t U_R1     = 10500320;   // 6400000 u32 = edge bf16 buf (e1/s2)
// total = 16900320 * 4 B = 67.6 MB

// ---------------- bf16 helpers (fp32 accumulate, RNE pack) ----------------
__device__ __forceinline__ void unpack2(uint u, float& a, float& b) {
    a = __uint_as_float(u << 16);
    b = __uint_as_float(u & 0xFFFF0000u);
}
__device__ __forceinline__ uint bfr(float f) {  // fp32 -> bf16 bits, round-nearest-even
    uint u = __float_as_uint(f);
    return (u + 0x7FFFu + ((u >> 16) & 1u)) >> 16;
}

// ---------------- CSR build ----------------

// histogram + per-incidence rank (rank writes coalesced).
// NOTE [measured r8/r9]: each global atomicAdd costs ~32B HBM write-through
// (memory-side execution); WRITE_SIZE ~112MB here is structural.
__global__ void k_hist_rank(const int* __restrict__ nidx, const int* __restrict__ eidx,
                            int* __restrict__ hist_n, int* __restrict__ hist_e,
                            int* __restrict__ rank_n, int* __restrict__ rank_e) {
    int i = blockIdx.x * blockDim.x + threadIdx.x;
    int stride = gridDim.x * blockDim.x;
    for (; i < N_INC_C; i += stride) {
        rank_e[i] = atomicAdd(&hist_e[eidx[i]], 1);
        rank_n[i] = atomicAdd(&hist_n[nidx[i]], 1);
    }
}

#define SCAN_ITEMS 8
#define SCAN_CHUNK 2048  // 256 threads * 8

__global__ __launch_bounds__(256) void k_scan_block_sums(const int* __restrict__ in,
                                                         int* __restrict__ bsum, int n) {
    __shared__ int lds[4];
    int base = blockIdx.x * SCAN_CHUNK + threadIdx.x * SCAN_ITEMS;
    int s = 0;
#pragma unroll
    for (int j = 0; j < SCAN_ITEMS; ++j) {
        int idx = base + j;
        s += (idx < n) ? in[idx] : 0;
    }
    for (int d = 1; d < 64; d <<= 1) s += __shfl_xor(s, d);
    if ((threadIdx.x & 63) == 0) lds[threadIdx.x >> 6] = s;
    __syncthreads();
    if (threadIdx.x == 0) bsum[blockIdx.x] = lds[0] + lds[1] + lds[2] + lds[3];
}

__global__ void k_scan_bsum(int* bsum, int nb) {
    int t = threadIdx.x;
    int v0 = (2 * t < nb) ? bsum[2 * t] : 0;
    int v1 = (2 * t + 1 < nb) ? bsum[2 * t + 1] : 0;
    int s = v0 + v1;
    int incl = s;
    for (int d = 1; d < 64; d <<= 1) {
        int u = __shfl_up(incl, d);
        if (t >= d) incl += u;
    }
    int excl = incl - s;
    if (2 * t < nb) bsum[2 * t] = excl;
    if (2 * t + 1 < nb) bsum[2 * t + 1] = excl + v0;
}

__global__ __launch_bounds__(256) void k_scan_write(const int* __restrict__ in,
                                                    const int* __restrict__ bsum,
                                                    int* __restrict__ rowptr, int n, int total) {
    __shared__ int wsum[4];
    int tid = threadIdx.x;
    int base = blockIdx.x * SCAN_CHUNK + tid * SCAN_ITEMS;
    int v[SCAN_ITEMS];
    int s = 0;
#pragma unroll
    for (int j = 0; j < SCAN_ITEMS; ++j) {
        int idx = base + j;
        v[j] = (idx < n) ? in[idx] : 0;
        s += v[j];
    }
    int incl = s;
    int lane = tid & 63;
    for (int d = 1; d < 64; d <<= 1) {
        int u = __shfl_up(incl, d);
        if (lane >= d) incl += u;
    }
    if (lane == 63) wsum[tid >> 6] = incl;
    __syncthreads();
    int woff = 0;
    int w = tid >> 6;
    for (int i = 0; i < w; ++i) woff += wsum[i];
    int excl = woff + (incl - s) + bsum[blockIdx.x];
#pragma unroll
    for (int j = 0; j < SCAN_ITEMS; ++j) {
        int idx = base + j;
        if (idx < n) rowptr[idx] = excl;
        excl += v[j];
    }
    if (blockIdx.x == 0 && tid == 0) rowptr[n] = total;
}

// fused placement: both CSR streams in one pass
__global__ void k_place(const int* __restrict__ nidx, const int* __restrict__ eidx,
                        const int* __restrict__ rank_e, const int* __restrict__ rank_n,
                        const int* __restrict__ rpe, const int* __restrict__ rpn,
                        int* __restrict__ csr_e_n, int* __restrict__ csr_n_e) {
    int i = blockIdx.x * blockDim.x + threadIdx.x;
    int stride = gridDim.x * blockDim.x;
    for (; i < N_INC_C; i += stride) {
        int n = nidx[i];
        int e = eidx[i];
        csr_e_n[rpe[e] + rank_e[i]] = n;
        csr_n_e[rpn[n] + rank_n[i]] = e;
    }
}

__global__ void k_coef(const float* __restrict__ w, const int* __restrict__ rpe,
                       float* __restrict__ coef) {
    int i = blockIdx.x * blockDim.x + threadIdx.x;
    if (i >= N_EDGES_C) return;
    int bd = rpe[i + 1] - rpe[i];
    coef[i] = (bd > 0) ? w[i] / (float)bd : 0.0f;
}

__global__ void k_dinv(const int* __restrict__ rpn, const int* __restrict__ csr_n_e,
                       const float* __restrict__ w, float* __restrict__ Dinv) {
    int i = blockIdx.x * blockDim.x + threadIdx.x;
    if (i >= N_NODES_C) return;
    int s0 = rpn[i], s1 = rpn[i + 1];
    float s = 0.0f;
    for (int k = s0; k < s1; ++k) s += w[csr_n_e[k]];
    Dinv[i] = (s > 0.0f) ? 1.0f / s : 0.0f;
}

// ---------------- register-tiled dense GEMM (fp32 compute) ----------------
// Y[nrows x N] = X[nrows x K] @ W[K x N] (+bias,relu if EPI)
// INBF: X is bf16; OUTBF: Y is bf16 (TN must be 4). 256 threads = 16x16 tile grid.
template <int K, int N, int BM, int TM, int TN, int EPI, int OUTBF, int INBF>
__global__ __launch_bounds__(256) void k_gemm_rt(const void* __restrict__ Xv,
                                                 const float* __restrict__ W,
                                                 const float* __restrict__ bias,
                                                 void* __restrict__ Yv, int nrows) {
    static_assert(16 * TN == N && 16 * TM == BM, "tile mismatch");
    __shared__ float Ws[K * N];
    __shared__ float Xs[BM][K + 4];

    int tid = threadIdx.x;
    int row0 = blockIdx.x * BM;

    for (int t = tid * 4; t < K * N; t += 1024)
        *reinterpret_cast<float4*>(&Ws[t]) = *reinterpret_cast<const float4*>(&W[t]);

    if (INBF) {
        const ushort* X = (const ushort*)Xv;
        for (int t = tid * 8; t < BM * K; t += 2048) {
            int r = t / K, k = t % K;
            int gr = row0 + r;
            uint4 v = make_uint4(0, 0, 0, 0);
            if (gr < nrows) v = *reinterpret_cast<const uint4*>(&X[(size_t)gr * K + k]);
            unpack2(v.x, Xs[r][k + 0], Xs[r][k + 1]);
            unpack2(v.y, Xs[r][k + 2], Xs[r][k + 3]);
            unpack2(v.z, Xs[r][k + 4], Xs[r][k + 5]);
            unpack2(v.w, Xs[r][k + 6], Xs[r][k + 7]);
        }
    } else {
        const float* X = (const float*)Xv;
        for (int t = tid * 4; t < BM * K; t += 1024) {
            int r = t / K, k = t % K;
            int gr = row0 + r;
            float4 v;
            if (gr < nrows) v = *reinterpret_cast<const float4*>(&X[(size_t)gr * K + k]);
            else { v.x = v.y = v.z = v.w = 0.0f; }
            *reinterpret_cast<float4*>(&Xs[r][k]) = v;
        }
    }
    __syncthreads();

    int tx = tid & 15;
    int ty = tid >> 4;
    float acc[TM][TN] = {};
#pragma unroll 8
    for (int k = 0; k < K; ++k) {
        float a[TM], b[TN];
#pragma unroll
        for (int m = 0; m < TM; ++m) a[m] = Xs[ty * TM + m][k];
#pragma unroll
        for (int n = 0; n < TN; ++n) b[n] = Ws[k * N + tx * TN + n];
#pragma unroll
        for (int m = 0; m < TM; ++m)
#pragma unroll
            for (int n = 0; n < TN; ++n) acc[m][n] += a[m] * b[n];
    }

#pragma unroll
    for (int m = 0; m < TM; ++m) {
        int gr = row0 + ty * TM + m;
        if (gr >= nrows) continue;
        if (OUTBF) {
            ushort* Y = (ushort*)Yv;
            uint2 o;
            o.x = bfr(acc[m][0]) | (bfr(acc[m][1]) << 16);
            o.y = bfr(acc[m][2]) | (bfr(acc[m][3]) << 16);
            *reinterpret_cast<uint2*>(&Y[(size_t)gr * N + tx * TN]) = o;
        } else {
            float* Y = (float*)Yv;
#pragma unroll
            for (int ng = 0; ng < TN / 4; ++ng) {
                float4 o;
                o.x = acc[m][ng * 4 + 0]; o.y = acc[m][ng * 4 + 1];
                o.z = acc[m][ng * 4 + 2]; o.w = acc[m][ng * 4 + 3];
                if (EPI) {
                    const float4 b4 = *reinterpret_cast<const float4*>(&bias[tx * TN + ng * 4]);
                    o.x += b4.x; o.y += b4.y; o.z += b4.z; o.w += b4.w;
                    o.x = o.x > 0.0f ? o.x : 0.0f;
                    o.y = o.y > 0.0f ? o.y : 0.0f;
                    o.z = o.z > 0.0f ? o.z : 0.0f;
                    o.w = o.w > 0.0f ? o.w : 0.0f;
                }
                *reinterpret_cast<float4*>(&Y[(size_t)gr * N + tx * TN + ng * 4]) = o;
            }
        }
    }
}

// ---------------- bf16 CSR gathers: 8 neighbor-groups x 8 lanes x bf16x8 ----------------
// Row = 64 bf16 (128 B): 8 lanes x 8 channels covers the row EXACTLY (r10 bug was 16 lanes).
// EN=0: dst[r] = sum src[c]; EN=1: dst[r] = Dinv[r]*sum coef[c]*src[c] (+bias,relu if FIN)
template <int EN, int FIN>
__global__ __launch_bounds__(256) void k_gather_bf(const int* __restrict__ rowptr,
                                                   const int* __restrict__ cols,
                                                   const float* __restrict__ coef,
                                                   const ushort* __restrict__ src,
                                                   const float* __restrict__ Dinv,
                                                   const float* __restrict__ bias,
                                                   ushort* __restrict__ dst, int nrows) {
    int wid = (blockIdx.x * 256 + threadIdx.x) >> 6;
    int lane = threadIdx.x & 63;
    int g = lane >> 3;        // neighbor group 0..7
    int gl = lane & 7;        // channels [gl*8, gl*8+8) -> 64 total
    int nw = (gridDim.x * 256) >> 6;
    for (int r = wid; r < nrows; r += nw) {
        int s0 = rowptr[r], s1 = rowptr[r + 1];
        float a[8] = {};
        for (int j = s0 + g; j < s1; j += 8) {
            int c = cols[j];  // uniform within group
            float s = EN ? coef[c] : 1.0f;
            const uint4 v = *reinterpret_cast<const uint4*>(&src[(size_t)c * 64 + gl * 8]);
            float f0, f1;
            unpack2(v.x, f0, f1); a[0] += s * f0; a[1] += s * f1;
            unpack2(v.y, f0, f1); a[2] += s * f0; a[3] += s * f1;
            unpack2(v.z, f0, f1); a[4] += s * f0; a[5] += s * f1;
            unpack2(v.w, f0, f1); a[6] += s * f0; a[7] += s * f1;
        }
        // reduce the 8 neighbor groups (xor over lane bits 3..5)
#pragma unroll
        for (int k = 0; k < 8; ++k) {
            a[k] += __shfl_xor(a[k], 8);
            a[k] += __shfl_xor(a[k], 16);
            a[k] += __shfl_xor(a[k], 32);
        }
        if (g == 0) {
            if (EN) {
                float dv = Dinv[r];
#pragma unroll
                for (int k = 0; k < 8; ++k) a[k] *= dv;
            }
            if (FIN) {
                const float4 b0 = *reinterpret_cast<const float4*>(&bias[gl * 8]);
                const float4 b1v = *reinterpret_cast<const float4*>(&bias[gl * 8 + 4]);
                a[0] += b0.x; a[1] += b0.y; a[2] += b0.z; a[3] += b0.w;
                a[4] += b1v.x; a[5] += b1v.y; a[6] += b1v.z; a[7] += b1v.w;
#pragma unroll
                for (int k = 0; k < 8; ++k) a[k] = a[k] > 0.0f ? a[k] : 0.0f;
            }
            uint4 o;
            o.x = bfr(a[0]) | (bfr(a[1]) << 16);
            o.y = bfr(a[2]) | (bfr(a[3]) << 16);
            o.z = bfr(a[4]) | (bfr(a[5]) << 16);
            o.w = bfr(a[6]) | (bfr(a[7]) << 16);
            *reinterpret_cast<uint4*>(&dst[(size_t)r * 64 + gl * 8]) = o;
        }
    }
}

// ---------------- host ----------------

extern "C" void kernel_launch(void* const* d_in, const int* in_sizes, int n_in,
                              void* d_out, int out_size, void* d_ws, size_t ws_size,
                              hipStream_t stream) {
    const float* x   = (const float*)d_in[0];
    const int*   eix = (const int*)d_in[1];
    const float* w   = (const float*)d_in[2];
    const float* W1  = (const float*)d_in[4];
    const float* b1  = (const float*)d_in[5];
    const float* W2  = (const float*)d_in[6];
    const float* b2  = (const float*)d_in[7];
    float* out = (float*)d_out;

    const int* nidx = eix;
    const int* eidx = eix + N_INC_C;

    int*   wsI = (int*)d_ws;
    float* wsF = (float*)d_ws;
    int* hist_e  = wsI + U_HIST_E;
    int* hist_n  = wsI + U_HIST_N;
    int* rpe     = wsI + U_RPE;
    int* rpn     = wsI + U_RPN;
    int* bsum    = wsI + U_BSUM;
    float* coef  = wsF + U_COEF;
    float* Dinv  = wsF + U_DINV;
    int* rank_e  = wsI + U_RANK_E;
    int* rank_n  = wsI + U_RANK_N;
    int* csr_e_n = wsI + U_CSR_EN;
    int* csr_n_e = wsI + U_CSR_NE;
    ushort* nbuf = (ushort*)(wsI + U_R2);  // h1 / g1 / t2  [N_NODES x 64] bf16
    ushort* ebuf = (ushort*)(wsI + U_R1);  // e1 / s2       [N_EDGES x 64] bf16
    ushort* h1 = nbuf; ushort* g1 = nbuf; ushort* t2 = nbuf;
    ushort* e1 = ebuf; ushort* s2 = ebuf;

    // ---- CSR build ----
    hipMemsetAsync(wsI, 0, 300000 * sizeof(int), stream);  // hist_e + hist_n
    k_hist_rank<<<2048, 256, 0, stream>>>(nidx, eidx, hist_n, hist_e, rank_n, rank_e);

    int nb_e = (N_EDGES_C + SCAN_CHUNK - 1) / SCAN_CHUNK;   // 98
    int nb_n = (N_NODES_C + SCAN_CHUNK - 1) / SCAN_CHUNK;   // 49
    k_scan_block_sums<<<nb_e, 256, 0, stream>>>(hist_e, bsum, N_EDGES_C);
    k_scan_bsum<<<1, 64, 0, stream>>>(bsum, nb_e);
    k_scan_write<<<nb_e, 256, 0, stream>>>(hist_e, bsum, rpe, N_EDGES_C, N_INC_C);
    k_scan_block_sums<<<nb_n, 256, 0, stream>>>(hist_n, bsum, N_NODES_C);
    k_scan_bsum<<<1, 64, 0, stream>>>(bsum, nb_n);
    k_scan_write<<<nb_n, 256, 0, stream>>>(hist_n, bsum, rpn, N_NODES_C, N_INC_C);

    k_place<<<2048, 256, 0, stream>>>(nidx, eidx, rank_e, rank_n, rpe, rpn, csr_e_n, csr_n_e);
    k_coef<<<(N_EDGES_C + 255) / 256, 256, 0, stream>>>(w, rpe, coef);
    k_dinv<<<(N_NODES_C + 255) / 256, 256, 0, stream>>>(rpn, csr_n_e, w, Dinv);

    // ---- layer 1 ----
    k_gemm_rt<F_IN_C, H1_C, 32, 2, 4, 0, 1, 0><<<(N_NODES_C + 31) / 32, 256, 0, stream>>>(
        x, W1, nullptr, h1, N_NODES_C);
    k_gather_bf<0, 0><<<(N_EDGES_C + 3) / 4, 256, 0, stream>>>(rpe, csr_e_n, nullptr, h1,
                                                               nullptr, nullptr, e1, N_EDGES_C);
    k_gather_bf<1, 1><<<(N_NODES_C + 3) / 4, 256, 0, stream>>>(rpn, csr_n_e, coef, e1,
                                                               Dinv, b1, g1, N_NODES_C);

    // ---- layer 2 (aggregate in 64-dim, project 64->128 last) ----
    k_gather_bf<0, 0><<<(N_EDGES_C + 3) / 4, 256, 0, stream>>>(rpe, csr_e_n, nullptr, g1,
                                                               nullptr, nullptr, s2, N_EDGES_C);
    k_gather_bf<1, 0><<<(N_NODES_C + 3) / 4, 256, 0, stream>>>(rpn, csr_n_e, coef, s2,
                                                               Dinv, nullptr, t2, N_NODES_C);
    k_gemm_rt<H1_C, H2_C, 64, 4, 8, 1, 0, 1><<<(N_NODES_C + 63) / 64, 256, 0, stream>>>(
        t2, W2, b2, out, N_NODES_C);
}